// Round 3
// baseline (54.523 us; speedup 1.0000x reference)
//
#include <hip/hip_runtime.h>

// FocalLoss, sparse exact evaluation, fully fused (2 dispatches, no memset).
// Loss is nonzero only at <=2048 positive + <=32768 sampled negative positions.
// Dedup with pos-priority: distinct key counts once; it counts as positive iff
// ANY positive candidate carries it (neg_mask *= 1-pos_mask). Each block owns a
// hash partition of the key space and dedups its keys in a private LDS table.

#define B_   2
#define L_   4096
#define S_   4096
#define P_   2048
#define N_   8
#define PN_  (P_ * N_)          // 16384
#define K_   (P_ + 2 * PN_)     // 34816 candidates
#define NB   128                // blocks = hash partitions (top 7 bits)
#define LSLOTS 1024             // LDS slots/block; E[keys/partition]=272 -> lf 0.27
#define LMASK  (LSLOTS - 1)
#define EMPTY  0xFFFFFFFFu
#define KMASK  0x01FFFFFFu      // keys < 2^25 (B*L*S = 2^25)
#define POSBIT 0x80000000u

__device__ __forceinline__ unsigned cand_key(int t,
    const int* __restrict__ b_ids, const int* __restrict__ i_ids,
    const int* __restrict__ j_ids, const int* __restrict__ rc,
    const int* __restrict__ rr) {
  if (t < P_) {
    return ((unsigned)b_ids[t] * L_ + (unsigned)i_ids[t]) * S_ + (unsigned)j_ids[t];
  } else if (t < P_ + PN_) {
    int u = t - P_;
    int p = u >> 3;                       // N_ == 8
    int col = rc[u];
    col += (col >= j_ids[p]) ? 1 : 0;     // torch: rand[rand >= idx] += 1
    return ((unsigned)b_ids[p] * L_ + (unsigned)i_ids[p]) * S_ + (unsigned)col;
  } else {
    int u = t - P_ - PN_;
    int p = u >> 3;
    int row = rr[u];
    row += (row >= i_ids[p]) ? 1 : 0;
    return ((unsigned)b_ids[p] * L_ + (unsigned)row) * S_ + (unsigned)j_ids[p];
  }
}

__global__ __launch_bounds__(256) void focal_fused(
    const float* __restrict__ conf,
    const int* __restrict__ b_ids, const int* __restrict__ i_ids,
    const int* __restrict__ j_ids, const int* __restrict__ rc,
    const int* __restrict__ rr,
    float* __restrict__ partial, unsigned* __restrict__ cnts) {
  __shared__ unsigned tab[LSLOTS];
  __shared__ float red[4];
  __shared__ unsigned redc[4];

  const int tid = threadIdx.x;
  for (int s = tid; s < LSLOTS; s += 256) tab[s] = EMPTY;
  __syncthreads();

  const unsigned mypart = blockIdx.x;   // top 7 hash bits

  // scan all candidates; insert mine into the LDS set
  for (int t = tid; t < K_; t += 256) {
    unsigned key  = cand_key(t, b_ids, i_ids, j_ids, rc, rr);
    unsigned hash = key * 2654435761u;
    if ((hash >> 25) != mypart) continue;
    unsigned val = key | ((t < P_) ? POSBIT : 0u);
    unsigned s = (hash >> 14) & LMASK;  // bits 14..23, disjoint from partition bits
    while (true) {
      unsigned cur = tab[s];
      if (cur != EMPTY && (cur & KMASK) == key) {
        if (val & POSBIT) atomicOr(&tab[s], POSBIT);
        break;
      }
      if (cur == EMPTY) {
        unsigned old = atomicCAS(&tab[s], EMPTY, val);
        if (old == EMPTY) break;
        if ((old & KMASK) == key) {
          if (val & POSBIT) atomicOr(&tab[s], POSBIT);
          break;
        }
      }
      s = (s + 1) & LMASK;
    }
  }
  __syncthreads();

  // sweep the table: gather conf, compute focal terms
  float term = 0.0f;
  unsigned cnt = 0;
  for (int s = tid; s < LSLOTS; s += 256) {
    unsigned e = tab[s];
    if (e != EMPTY) {
      bool is_pos = (e & POSBIT) != 0;
      float cv = conf[e & KMASK];
      float p = fminf(fmaxf(cv, 1e-7f), 1.0f - 1e-7f);
      term += is_pos ? (-0.25f * (1.0f - p) * (1.0f - p) * logf(p))
                     : (-0.75f * p * p * logf(1.0f - p));
      cnt += is_pos ? 1u : 0u;
    }
  }

  // block reduction
  #pragma unroll
  for (int off = 32; off; off >>= 1) {
    term += __shfl_down(term, off);
    cnt  += __shfl_down(cnt, off);
  }
  if ((tid & 63) == 0) { red[tid >> 6] = term; redc[tid >> 6] = cnt; }
  __syncthreads();
  if (tid == 0) {
    partial[blockIdx.x] = red[0] + red[1] + red[2] + red[3];
    cnts[blockIdx.x]    = redc[0] + redc[1] + redc[2] + redc[3];
  }
}

__global__ __launch_bounds__(64) void focal_finalize(
    const float* __restrict__ partial, const unsigned* __restrict__ cnts,
    float* __restrict__ out) {
  int tid = threadIdx.x;                 // one wave
  float s = partial[tid] + partial[tid + 64];
  unsigned c = cnts[tid] + cnts[tid + 64];
  #pragma unroll
  for (int off = 32; off; off >>= 1) {
    s += __shfl_down(s, off);
    c += __shfl_down(c, off);
  }
  if (tid == 0) out[0] = s / (float)c;
}

extern "C" void kernel_launch(void* const* d_in, const int* in_sizes, int n_in,
                              void* d_out, int out_size, void* d_ws, size_t ws_size,
                              hipStream_t stream) {
  const float* conf  = (const float*)d_in[0];
  const int*   b_ids = (const int*)d_in[1];
  const int*   i_ids = (const int*)d_in[2];
  const int*   j_ids = (const int*)d_in[3];
  const int*   rc    = (const int*)d_in[4];
  const int*   rr    = (const int*)d_in[5];

  float*    partial = (float*)d_ws;            // NB floats
  unsigned* cnts    = (unsigned*)d_ws + NB;    // NB uints (1KB total)

  focal_fused<<<NB, 256, 0, stream>>>(conf, b_ids, i_ids, j_ids, rc, rr,
                                      partial, cnts);
  focal_finalize<<<1, 64, 0, stream>>>(partial, cnts, (float*)d_out);
}